// Round 16
// baseline (2869.297 us; speedup 1.0000x reference)
//
#include <hip/hip_runtime.h>

typedef _Float16 v8h __attribute__((ext_vector_type(8)));
typedef float v4f __attribute__((ext_vector_type(4)));

#define NT 512
#define XSTR 344   // x row stride (halves)
#define HSTR 1032  // h row stride (halves)

// ws layout:
//  W1H [site gp, 0..79][512 tid][8] halves at 0 | W1L at 327680
//  W2H [site s, 0..63][512 tid][8] at 655360 | W2L at 917504
//  att (t-major actions, float) at byte 2359296 (64 MB)
//  ysc (t-major trajectories, float) at byte 69468160 (268 MB)
static constexpr size_t ATT_BYTES_NEEDED = 2359296ull + 67108864ull;
static constexpr size_t YSC_OFF = 69468160ull;
static constexpr size_t YSC_BYTES_NEEDED = YSC_OFF + 268435456ull;

#define MFMA16 __builtin_amdgcn_mfma_f32_16x16x32_f16

#define GLOAD(dst, base, vo) \
  asm volatile("global_load_dwordx4 %0, %1, %2" : "=v"(dst) : "v"(vo), "s"(base))
#define VMW_(n) asm volatile("s_waitcnt vmcnt(" #n ")" ::: "memory")
#define VMW(n) do { VMW_(n); __builtin_amdgcn_sched_barrier(0); } while (0)
#define LGKMBAR() do { asm volatile("s_waitcnt lgkmcnt(0)" ::: "memory"); \
  __builtin_amdgcn_s_barrier(); } while (0)

__device__ __forceinline__ float tanh_fast(float a) {
  float e = __expf(2.0f * a);
  return 1.0f - __fdividef(2.0f, e + 1.0f);
}

extern "C" __global__ void conv_w(const float* __restrict__ W1,
                                  const float* __restrict__ W2,
                                  _Float16* __restrict__ ws) {
  int i = blockIdx.x * 256 + threadIdx.x;        // 917504 total
  if (i < 327680) {
    int j = i & 7, lane = (i >> 3) & 63, w = (i >> 9) & 7, gp = i >> 12;
    int g = lane >> 4, l15 = lane & 15;
    int ph = gp / 10, p = gp % 10;
    float v = W1[(p * 32 + g * 8 + j) * 1024 + ph * 128 + w * 16 + l15];
    _Float16 hh = (_Float16)v;
    ws[i] = hh;
    ws[327680 + i] = (_Float16)((v - (float)hh) * 2048.f);
  } else {
    int iq = i - 655360;
    if (iq >= 0) {
      int j = iq & 7, t = (iq >> 3) & 511, s = iq >> 12;
      int lane = t & 63, wave = t >> 6, g = lane >> 4, l15 = lane & 15;
      int p = s >> 1, ph2 = s & 1;
      float v = W2[(p * 32 + g * 8 + j) * 256 + ph2 * 128 + wave * 16 + l15];
      _Float16 hh = (_Float16)v;
      ws[655360 + iq] = hh;
      ws[917504 + iq] = (_Float16)((v - (float)hh) * 2048.f);
    }
  }
}

extern "C" __global__ void conv_a(const float* __restrict__ actions,
                                  float* __restrict__ att) {
  size_t o = (size_t)blockIdx.x * 256 + threadIdx.x;
  int f = (int)(o & 63);
  int b = (int)((o >> 6) & 4095);
  int t = (int)(o >> 18);
  att[o] = actions[((size_t)b * 64 + f) * 64 + t];
}

// transpose ysc[t][b][c] -> out[b][c][t]; coalesced both sides
extern "C" __global__ void tr_out(const float* __restrict__ ysc,
                                  float* __restrict__ out) {
  __shared__ float tile[256][65];
  const int b = blockIdx.x, tid = threadIdx.x;
  // load: thread tid = column c; 64 coalesced row-loads
  #pragma unroll 8
  for (int t = 0; t < 64; ++t)
    tile[tid][t] = ysc[(size_t)t * 1048576 + (size_t)b * 256 + tid];
  __syncthreads();
  // store: wave w handles c = w*64..w*64+63; lane l writes t=l (contiguous)
  const int w = tid >> 6, l = tid & 63;
  #pragma unroll 8
  for (int cc = 0; cc < 64; ++cc) {
    int c = w * 64 + cc;
    out[(size_t)b * 16384 + (size_t)c * 64 + l] = tile[c][l];
  }
}

#define G1BODY(p, RF, N, RD0) do { \
    VMW(N); \
    v8h bh = B1H[(p) % 5], bl = B1L[(p) % 5]; \
    if (RF) { GLOAD(B1H[(p) % 5], w1hB, vo1); GLOAD(B1L[(p) % 5], w1lB, vo1); \
              vo1 += 8192; if (vo1 == vend1) vo1 = tid16; } \
    v8h xch = Xh[(p) & 1], xcl = Xl[(p) & 1]; \
    if ((p) < 9) { \
      Xh[((p) + 1) & 1] = *(const v8h*)&xHs[xbase + ((p) + 1) * 32]; \
      Xl[((p) + 1) & 1] = *(const v8h*)&xLs[xbase + ((p) + 1) * 32]; \
    } else if (RD0) { \
      Xh[0] = *(const v8h*)&xHs[xbase]; \
      Xl[0] = *(const v8h*)&xLs[xbase]; \
    } \
    accH = MFMA16(xch, bh, accH, 0, 0, 0); \
    accM = MFMA16(xch, bl, accM, 0, 0, 0); \
    accM = MFMA16(xcl, bh, accM, 0, 0, 0); \
  } while (0)

#define B2PRO(k, off) do { \
    GLOAD(B2H0[k], w2hB, (off)); \
    GLOAD(B2L0[k], w2lB, (off)); \
    GLOAD(B2H1[k], w2hB, (off) + 8192); \
    GLOAD(B2L1[k], w2lB, (off) + 8192); \
  } while (0)

#define G2BODY(j, s3, par, RF, RD, N) do { \
    VMW(N); \
    v8h bh0 = B2H0[s3], bl0 = B2L0[s3]; \
    v8h bh1 = B2H1[s3], bl1 = B2L1[s3]; \
    if (RF) { \
      GLOAD(B2H0[s3], w2hB, vo2); GLOAD(B2L0[s3], w2lB, vo2); \
      GLOAD(B2H1[s3], w2hB, vo2 + 8192); GLOAD(B2L1[s3], w2lB, vo2 + 8192); \
      vo2 += 16384; if (vo2 == vend2) vo2 = tid16; \
    } \
    v8h hch = Hh[par], hcl = Hl_[par]; \
    if (RD) { \
      Hh[(par) ^ 1]  = *(const v8h*)&hHs[hbase + hnx]; \
      Hl_[(par) ^ 1] = *(const v8h*)&hLs[hbase + hnx]; \
      hnx = (hnx + 32) & 1023; \
    } \
    c0H = MFMA16(hch, bh0, c0H, 0, 0, 0); \
    c0M = MFMA16(hch, bl0, c0M, 0, 0, 0); \
    c0M = MFMA16(hcl, bh0, c0M, 0, 0, 0); \
    c1H = MFMA16(hch, bh1, c1H, 0, 0, 0); \
    c1M = MFMA16(hch, bl1, c1M, 0, 0, 0); \
    c1M = MFMA16(hcl, bh1, c1M, 0, 0, 0); \
  } while (0)

// x-phase y-write helper (shared shape)
#define XWRITE(m, va, vb) do { \
    _Float16 h0 = (_Float16)(va); \
    xHs[(m) * XSTR + 64 + nloc] = h0; \
    xLs[(m) * XSTR + 64 + nloc] = (_Float16)(((va) - (float)h0) * 2048.f); \
    _Float16 h1 = (_Float16)(vb); \
    xHs[(m) * XSTR + 192 + nloc] = h1; \
    xLs[(m) * XSTR + 192 + nloc] = (_Float16)(((vb) - (float)h1) * 2048.f); \
  } while (0)

// ================== BR=8 kernel: 2 blocks/CU, ysc stores ==================
extern "C" __global__ void __launch_bounds__(NT, 2)
ode8(const float* __restrict__ att, const float* __restrict__ y0,
     const float* __restrict__ b1f, const float* __restrict__ b2f,
     const float* __restrict__ dtp, const _Float16* __restrict__ ws,
     float* __restrict__ ysc)
{
  __shared__ __align__(16) _Float16 xHs[8 * XSTR], xLs[8 * XSTR];
  __shared__ __align__(16) _Float16 hHs[8 * HSTR], hLs[8 * HSTR];
  __shared__ float b1s[1024];

  const int tid  = threadIdx.x;
  const int lane = tid & 63;
  const int l15  = lane & 15, g = lane >> 4;
  const int act  = g < 2;
  const int nloc = (tid >> 6) * 16 + l15;
  const int b0   = blockIdx.x * 8;
  const float dt = dtp[0];
  const int tid16 = tid * 16;

  const int rot8  = (blockIdx.x >> 3) & 7;
  const int rot2c = (blockIdx.x >> 3) & 31;
  const int vend1 = tid16 + 655360;
  const int vend2 = tid16 + 524288;

  const _Float16* w1hB = ws;
  const _Float16* w1lB = ws + 327680;
  const _Float16* w2hB = ws + 655360;
  const _Float16* w2lB = ws + 917504;

  for (int i = tid; i < 1024; i += NT) b1s[i] = b1f[i];
  const float b2r0 = b2f[nloc], b2r1 = b2f[128 + nloc];

  float ya[4], yb[4];
  #pragma unroll
  for (int j = 0; j < 4; ++j) {
    int m = (g * 4 + j) & 7;
    ya[j] = y0[(size_t)(b0 + m) * 256 + nloc];
    yb[j] = y0[(size_t)(b0 + m) * 256 + 128 + nloc];
    if (act) {
      ysc[(size_t)(b0 + m) * 256 + nloc] = ya[j];
      ysc[(size_t)(b0 + m) * 256 + 128 + nloc] = yb[j];
    }
  }

  const int xbase = l15 * XSTR + g * 8;
  const int hbase = l15 * HSTR + g * 8;

  v8h B1H[5], B1L[5];
  v8h B2H0[3], B2L0[3], B2H1[3], B2L1[3];
  v8h Xh[2], Xl[2], Hh[2], Hl_[2];

  const int g1p0 = tid16 + rot8 * 81920;
  #pragma unroll
  for (int s = 0; s < 5; ++s) {
    GLOAD(B1H[s], w1hB, g1p0 + s * 8192);
    GLOAD(B1L[s], w1lB, g1p0 + s * 8192);
  }

  #pragma unroll 1
  for (int t = 0; t < 63; ++t) {
    {
      int m = tid >> 6, k = tid & 63;
      float v = att[((size_t)t * 4096 + b0 + m) * 64 + k];
      _Float16 hh = (_Float16)v;
      xHs[m * XSTR + k] = hh;
      xLs[m * XSTR + k] = (_Float16)((v - (float)hh) * 2048.f);
    }
    if (act) {
      #pragma unroll
      for (int j = 0; j < 4; ++j) XWRITE(g * 4 + j, ya[j], yb[j]);
    }
    LGKMBAR();

    Xh[0] = *(const v8h*)&xHs[xbase];
    Xl[0] = *(const v8h*)&xLs[xbase];

    int vo1 = g1p0 + 5 * 8192;

    #pragma unroll 1
    for (int ph = 0; ph < 7; ++ph) {
      const int pha = (ph + rot8) & 7;
      const float bb = b1s[pha * 128 + nloc];
      v4f accH = v4f{bb, bb, bb, bb};
      v4f accM = v4f{0.f, 0.f, 0.f, 0.f};
      #pragma unroll
      for (int p = 0; p < 10; ++p) G1BODY(p, 1, 8, 1);
      if (act) {
        #pragma unroll
        for (int j = 0; j < 4; ++j) {
          float v = accH[j] + accM[j] * (1.f / 2048.f);
          float th = tanh_fast(v);
          _Float16 hh = (_Float16)th;
          int m = g * 4 + j;
          hHs[m * HSTR + pha * 128 + nloc] = hh;
          hLs[m * HSTR + pha * 128 + nloc] = (_Float16)((th - (float)hh) * 2048.f);
        }
      }
    }
    {
      const int pha = (7 + rot8) & 7;
      const float bb = b1s[pha * 128 + nloc];
      v4f accH = v4f{bb, bb, bb, bb};
      v4f accM = v4f{0.f, 0.f, 0.f, 0.f};
      #pragma unroll
      for (int p = 0; p < 6; ++p) G1BODY(p, (p) < 5, 8, 1);
      G1BODY(6, 0, 6, 1);
      B2PRO(0, tid16 + ((rot2c + 0) & 31) * 16384);
      G1BODY(7, 0, 8, 1);
      B2PRO(1, tid16 + ((rot2c + 1) & 31) * 16384);
      G1BODY(8, 0, 10, 1);
      B2PRO(2, tid16 + ((rot2c + 2) & 31) * 16384);
      G1BODY(9, 0, 12, 0);
      if (act) {
        #pragma unroll
        for (int j = 0; j < 4; ++j) {
          float v = accH[j] + accM[j] * (1.f / 2048.f);
          float th = tanh_fast(v);
          _Float16 hh = (_Float16)th;
          int m = g * 4 + j;
          hHs[m * HSTR + pha * 128 + nloc] = hh;
          hLs[m * HSTR + pha * 128 + nloc] = (_Float16)((th - (float)hh) * 2048.f);
        }
      }
    }
    LGKMBAR();

    int hnx = ((rot2c + 1) & 31) * 32;
    Hh[0]  = *(const v8h*)&hHs[hbase + rot2c * 32];
    Hl_[0] = *(const v8h*)&hLs[hbase + rot2c * 32];

    int vo2 = tid16 + ((rot2c + 3) & 31) * 16384;

    v4f c0H = v4f{b2r0, b2r0, b2r0, b2r0}, c0M = v4f{0.f, 0.f, 0.f, 0.f};
    v4f c1H = v4f{b2r1, b2r1, b2r1, b2r1}, c1M = v4f{0.f, 0.f, 0.f, 0.f};

    #pragma unroll 1
    for (int jj = 0; jj < 4; ++jj) {
      const int jb = jj * 6;
      G2BODY(jb + 0, 0, 0, 1, 1, 8);
      G2BODY(jb + 1, 1, 1, 1, 1, 8);
      G2BODY(jb + 2, 2, 0, 1, 1, 8);
      G2BODY(jb + 3, 0, 1, 1, 1, 8);
      G2BODY(jb + 4, 1, 0, 1, 1, 8);
      G2BODY(jb + 5, 2, 1, 1, 1, 8);
    }
    G2BODY(24, 0, 0, 1, 1, 8);
    G2BODY(25, 1, 1, 1, 1, 8);
    G2BODY(26, 2, 0, 1, 1, 8);
    G2BODY(27, 0, 1, 1, 1, 8);
    G2BODY(28, 1, 0, 1, 1, 8);
    G2BODY(29, 2, 1, 0, 1, 8);
    G2BODY(30, 0, 0, 0, 1, 4);
    G2BODY(31, 1, 1, 0, 0, 0);

    #pragma unroll
    for (int j = 0; j < 4; ++j) {
      int m = g * 4 + j;
      float yn0 = ya[j] + dt * (c0H[j] + c0M[j] * (1.f / 2048.f));
      float yn1 = yb[j] + dt * (c1H[j] + c1M[j] * (1.f / 2048.f));
      ya[j] = yn0; yb[j] = yn1;
      if (act) {
        ysc[(size_t)(t + 1) * 1048576 + (size_t)(b0 + m) * 256 + nloc] = yn0;
        ysc[(size_t)(t + 1) * 1048576 + (size_t)(b0 + m) * 256 + 128 + nloc] = yn1;
      }
    }
    if (t < 62) {
      #pragma unroll
      for (int s = 0; s < 5; ++s) {
        GLOAD(B1H[s], w1hB, g1p0 + s * 8192);
        GLOAD(B1L[s], w1lB, g1p0 + s * 8192);
      }
    }
  }
}

// ================== BR=16 fallback: R14 verbatim ==================
extern "C" __global__ void __launch_bounds__(NT, 2)
ode16(const float* __restrict__ actions, const float* __restrict__ att,
      const float* __restrict__ y0,
      const float* __restrict__ b1f, const float* __restrict__ b2f,
      const float* __restrict__ dtp, const _Float16* __restrict__ ws,
      float* __restrict__ out)
{
  __shared__ __align__(16) _Float16 xHs[16 * XSTR], xLs[16 * XSTR];
  __shared__ __align__(16) _Float16 hHs[16 * HSTR], hLs[16 * HSTR];
  __shared__ float b1s[1024];

  const int tid  = threadIdx.x;
  const int lane = tid & 63;
  const int l15  = lane & 15, g = lane >> 4;
  const int nloc = (tid >> 6) * 16 + l15;
  const int b0   = blockIdx.x * 16;
  const float dt = dtp[0];
  const int tid16 = tid * 16;

  const int rot8  = (blockIdx.x >> 3) & 7;
  const int rot2c = (blockIdx.x >> 3) & 31;
  const int vend1 = tid16 + 655360;
  const int vend2 = tid16 + 524288;

  const _Float16* w1hB = ws;
  const _Float16* w1lB = ws + 327680;
  const _Float16* w2hB = ws + 655360;
  const _Float16* w2lB = ws + 917504;

  for (int i = tid; i < 1024; i += NT) b1s[i] = b1f[i];
  const float b2r0 = b2f[nloc], b2r1 = b2f[128 + nloc];

  float ya[4], yb[4];
  #pragma unroll
  for (int j = 0; j < 4; ++j) {
    int m = g * 4 + j;
    ya[j] = y0[(size_t)(b0 + m) * 256 + nloc];
    yb[j] = y0[(size_t)(b0 + m) * 256 + 128 + nloc];
    out[((size_t)((b0 + m) * 256 + nloc)) * 64] = ya[j];
    out[((size_t)((b0 + m) * 256 + 128 + nloc)) * 64] = yb[j];
  }

  const int xbase = l15 * XSTR + g * 8;
  const int hbase = l15 * HSTR + g * 8;

  v8h B1H[5], B1L[5];
  v8h B2H0[3], B2L0[3], B2H1[3], B2L1[3];
  v8h Xh[2], Xl[2], Hh[2], Hl_[2];

  const int g1p0 = tid16 + rot8 * 81920;
  #pragma unroll
  for (int s = 0; s < 5; ++s) {
    GLOAD(B1H[s], w1hB, g1p0 + s * 8192);
    GLOAD(B1L[s], w1lB, g1p0 + s * 8192);
  }

  #pragma unroll 1
  for (int t = 0; t < 63; ++t) {
    #pragma unroll
    for (int it = 0; it < 2; ++it) {
      int o = tid + NT * it;
      int m = o >> 6, k = o & 63;
      float v = att ? att[((size_t)t * 4096 + b0 + m) * 64 + k]
                    : actions[((size_t)(b0 + m) * 64 + k) * 64 + t];
      _Float16 hh = (_Float16)v;
      xHs[m * XSTR + k] = hh;
      xLs[m * XSTR + k] = (_Float16)((v - (float)hh) * 2048.f);
    }
    #pragma unroll
    for (int j = 0; j < 4; ++j) XWRITE(g * 4 + j, ya[j], yb[j]);
    LGKMBAR();

    Xh[0] = *(const v8h*)&xHs[xbase];
    Xl[0] = *(const v8h*)&xLs[xbase];

    int vo1 = g1p0 + 5 * 8192;

    #pragma unroll 1
    for (int ph = 0; ph < 7; ++ph) {
      const int pha = (ph + rot8) & 7;
      const float bb = b1s[pha * 128 + nloc];
      v4f accH = v4f{bb, bb, bb, bb};
      v4f accM = v4f{0.f, 0.f, 0.f, 0.f};
      #pragma unroll
      for (int p = 0; p < 10; ++p) G1BODY(p, 1, 8, 1);
      #pragma unroll
      for (int j = 0; j < 4; ++j) {
        float v = accH[j] + accM[j] * (1.f / 2048.f);
        float th = tanh_fast(v);
        _Float16 hh = (_Float16)th;
        int m = g * 4 + j;
        hHs[m * HSTR + pha * 128 + nloc] = hh;
        hLs[m * HSTR + pha * 128 + nloc] = (_Float16)((th - (float)hh) * 2048.f);
      }
    }
    {
      const int pha = (7 + rot8) & 7;
      const float bb = b1s[pha * 128 + nloc];
      v4f accH = v4f{bb, bb, bb, bb};
      v4f accM = v4f{0.f, 0.f, 0.f, 0.f};
      #pragma unroll
      for (int p = 0; p < 6; ++p) G1BODY(p, (p) < 5, 8, 1);
      G1BODY(6, 0, 6, 1);
      B2PRO(0, tid16 + ((rot2c + 0) & 31) * 16384);
      G1BODY(7, 0, 8, 1);
      B2PRO(1, tid16 + ((rot2c + 1) & 31) * 16384);
      G1BODY(8, 0, 10, 1);
      B2PRO(2, tid16 + ((rot2c + 2) & 31) * 16384);
      G1BODY(9, 0, 12, 0);
      #pragma unroll
      for (int j = 0; j < 4; ++j) {
        float v = accH[j] + accM[j] * (1.f / 2048.f);
        float th = tanh_fast(v);
        _Float16 hh = (_Float16)th;
        int m = g * 4 + j;
        hHs[m * HSTR + pha * 128 + nloc] = hh;
        hLs[m * HSTR + pha * 128 + nloc] = (_Float16)((th - (float)hh) * 2048.f);
      }
    }
    LGKMBAR();

    int hnx = ((rot2c + 1) & 31) * 32;
    Hh[0]  = *(const v8h*)&hHs[hbase + rot2c * 32];
    Hl_[0] = *(const v8h*)&hLs[hbase + rot2c * 32];

    int vo2 = tid16 + ((rot2c + 3) & 31) * 16384;

    v4f c0H = v4f{b2r0, b2r0, b2r0, b2r0}, c0M = v4f{0.f, 0.f, 0.f, 0.f};
    v4f c1H = v4f{b2r1, b2r1, b2r1, b2r1}, c1M = v4f{0.f, 0.f, 0.f, 0.f};

    #pragma unroll 1
    for (int jj = 0; jj < 4; ++jj) {
      const int jb = jj * 6;
      G2BODY(jb + 0, 0, 0, 1, 1, 8);
      G2BODY(jb + 1, 1, 1, 1, 1, 8);
      G2BODY(jb + 2, 2, 0, 1, 1, 8);
      G2BODY(jb + 3, 0, 1, 1, 1, 8);
      G2BODY(jb + 4, 1, 0, 1, 1, 8);
      G2BODY(jb + 5, 2, 1, 1, 1, 8);
    }
    G2BODY(24, 0, 0, 1, 1, 8);
    G2BODY(25, 1, 1, 1, 1, 8);
    G2BODY(26, 2, 0, 1, 1, 8);
    G2BODY(27, 0, 1, 1, 1, 8);
    G2BODY(28, 1, 0, 1, 1, 8);
    G2BODY(29, 2, 1, 0, 1, 8);
    G2BODY(30, 0, 0, 0, 1, 4);
    G2BODY(31, 1, 1, 0, 0, 0);

    #pragma unroll
    for (int j = 0; j < 4; ++j) {
      int m = g * 4 + j;
      float yn0 = ya[j] + dt * (c0H[j] + c0M[j] * (1.f / 2048.f));
      ya[j] = yn0;
      out[((size_t)((b0 + m) * 256 + nloc)) * 64 + (t + 1)] = yn0;
      float yn1 = yb[j] + dt * (c1H[j] + c1M[j] * (1.f / 2048.f));
      yb[j] = yn1;
      out[((size_t)((b0 + m) * 256 + 128 + nloc)) * 64 + (t + 1)] = yn1;
    }
    if (t < 62) {
      #pragma unroll
      for (int s = 0; s < 5; ++s) {
        GLOAD(B1H[s], w1hB, g1p0 + s * 8192);
        GLOAD(B1L[s], w1lB, g1p0 + s * 8192);
      }
    }
  }
}

extern "C" void kernel_launch(void* const* d_in, const int* in_sizes, int n_in,
                              void* d_out, int out_size, void* d_ws, size_t ws_size,
                              hipStream_t stream) {
  const float* actions = (const float*)d_in[1];
  const float* y0      = (const float*)d_in[2];
  const float* W1      = (const float*)d_in[3];
  const float* b1      = (const float*)d_in[4];
  const float* W2      = (const float*)d_in[5];
  const float* b2      = (const float*)d_in[6];
  const float* dtp     = (const float*)d_in[7];
  float* out = (float*)d_out;
  _Float16* ws = (_Float16*)d_ws;

  const bool use_att = ws_size >= ATT_BYTES_NEEDED;
  const bool use_ysc = ws_size >= YSC_BYTES_NEEDED;
  float* att = use_att ? (float*)((char*)d_ws + 2359296) : nullptr;
  float* ysc = use_ysc ? (float*)((char*)d_ws + YSC_OFF) : nullptr;

  hipLaunchKernelGGL(conv_w, dim3(3584), dim3(256), 0, stream, W1, W2, ws);
  if (use_att)
    hipLaunchKernelGGL(conv_a, dim3(65536), dim3(256), 0, stream, actions, att);

  if (use_att && use_ysc) {
    hipLaunchKernelGGL(ode8, dim3(512), dim3(NT), 0, stream,
                       att, y0, b1, b2, dtp, ws, ysc);
    hipLaunchKernelGGL(tr_out, dim3(4096), dim3(256), 0, stream, ysc, out);
  } else {
    hipLaunchKernelGGL(ode16, dim3(256), dim3(NT), 0, stream,
                       actions, att, y0, b1, b2, dtp, ws, out);
  }
}